// Round 6
// baseline (359.358 us; speedup 1.0000x reference)
//
#include <hip/hip_runtime.h>
#include <cstdint>
#include <cstddef>

#define NV 4096
#define NE 8192
#define INV 128
#define OUTV 128
#define INE 64

#define BK 64
#define NT (NE / BK)        // 128 K-tiles
#define HALF_B 16384        // 128 rows x 64 bf16 x 2B
#define LDS_BYTES (9 * HALF_B)  // 5 A-slots + 4 B-slots = 144 KiB

typedef __bf16 bf16x8 __attribute__((ext_vector_type(8)));
typedef float f32x4 __attribute__((ext_vector_type(4)));
typedef float f32x16 __attribute__((ext_vector_type(16)));

__device__ __forceinline__ uint16_t f2bf(float x) {
  uint32_t u = __builtin_bit_cast(uint32_t, x);
  u += 0x7fff + ((u >> 16) & 1);
  return (uint16_t)(u >> 16);
}

// d[e] = dot(H_e[e, :64], p[:64]); one wave per row
__global__ void k_diag(const float* __restrict__ He, const float* __restrict__ p,
                       float* __restrict__ d) {
  int lane = threadIdx.x & 63;
  int wid = threadIdx.x >> 6;
  int row = blockIdx.x * 4 + wid;
  float v = He[(size_t)row * INE + lane] * p[lane];
#pragma unroll
  for (int off = 32; off; off >>= 1) v += __shfl_xor(v, off);
  if (lane == 0) d[row] = v;
}

// Abf = bf16(T * d[col]), Bbf = bf16(T)   (both [NV][NE] row-major)
__global__ void k_prep(const float4* __restrict__ T4, const float4* __restrict__ d4,
                       ushort4* __restrict__ A4, ushort4* __restrict__ B4) {
  const size_t total = (size_t)NV * NE / 4;
  size_t stride = (size_t)gridDim.x * blockDim.x;
  for (size_t i = (size_t)blockIdx.x * blockDim.x + threadIdx.x; i < total; i += stride) {
    float4 t = T4[i];
    float4 dv = d4[i & (NE / 4 - 1)];
    ushort4 a, b;
    b.x = f2bf(t.x); b.y = f2bf(t.y); b.z = f2bf(t.z); b.w = f2bf(t.w);
    a.x = f2bf(t.x * dv.x); a.y = f2bf(t.y * dv.y);
    a.z = f2bf(t.z * dv.z); a.w = f2bf(t.w * dv.w);
    A4[i] = a;
    B4[i] = b;
  }
}

// XT[n][m] = bf16( sum_k H_v[m][k] * W[k][n] )   (X^T, [OUTV][NV])
__global__ void k_xw(const float* __restrict__ Hv, const float* __restrict__ W,
                     uint16_t* __restrict__ XT) {
  __shared__ float row[INV];
  int m = blockIdx.x;
  int n = threadIdx.x;  // 128 threads
  row[n] = Hv[(size_t)m * INV + n];
  __syncthreads();
  float acc = 0.f;
#pragma unroll 8
  for (int k = 0; k < INV; ++k) acc += row[k] * W[k * OUTV + n];
  XT[(size_t)n * NV + m] = f2bf(acc);
}

// ---- 256x256x64 bf16 GEMM, 1 barrier/K-tile, 32x32x16 MFMA, parity ping-pong ----
// C = A @ B^T over K=NE; epilogue: diag->1, * adj_v, store bf16

// stage one 128-row x 64-col half-tile; linear LDS dest, inverse-swizzled
// global source (slot ^= row&7 at 16B granularity within the 128B row).
__device__ __forceinline__ void stage_half(const uint16_t* __restrict__ G, int grow0,
                                           int ktile, char* lds_base, int tid) {
#pragma unroll
  for (int i = 0; i < 2; ++i) {
    int idx = i * 512 + tid;
    int row = idx >> 3;
    int slot = (idx & 7) ^ (row & 7);
    const char* src = (const char*)G +
        ((size_t)(grow0 + row) * NE + (size_t)ktile * BK) * 2 + slot * 16;
    __builtin_amdgcn_global_load_lds(
        (const __attribute__((address_space(1))) uint32_t*)src,
        (__attribute__((address_space(3))) uint32_t*)(lds_base + idx * 16), 16, 0, 0);
  }
}

__device__ __forceinline__ bf16x8 ld_frag(const char* half_base, int row, int g) {
  return *(const bf16x8*)(half_base + row * 128 + ((g ^ (row & 7)) << 4));
}

__global__ __launch_bounds__(512, 2) void k_gemm1(const uint16_t* __restrict__ A,
                                                  const uint16_t* __restrict__ B,
                                                  const float* __restrict__ adj_v,
                                                  uint16_t* __restrict__ adjA) {
  extern __shared__ char smem[];
  char* Aslot = smem;                 // 5 x HALF_B
  char* Bslot = smem + 5 * HALF_B;    // 4 x HALF_B

  const int tid = threadIdx.x;
  const int lane = tid & 63, wid = tid >> 6;
  const int wr = wid >> 2, wc = wid & 3;
  const int lc = lane & 31, lh = lane >> 5;
  const int bcol0 = (wc & 1) * 64;
  const int par = (wid >> 2) & 1;  // SIMD pair {wid, wid+4} gets both parities

  // XCD-aware swizzle: 256 blocks -> 8 chunks of 32; each chunk a 4(bi) x 8(bj) rect
  int bid = blockIdx.x;
  int xcd = bid & 7, cid = bid >> 3;
  int bi = (xcd >> 1) * 4 + (cid >> 3);
  int bj = (xcd & 1) * 8 + (cid & 7);

  const int arow0 = bi * 256, brow0 = bj * 256;

  f32x16 acc[4][2] = {};
  bf16x8 afA[2][4], afB[2][4], bfA[4], bfB[4];

  // ---- prologue: tile0 all halves + A0(tile1)
  stage_half(A, arow0, 0, Aslot + 0 * HALF_B, tid);
  stage_half(A, arow0 + 128, 0, Aslot + 1 * HALF_B, tid);
  stage_half(B, brow0, 0, Bslot + 0 * HALF_B, tid);
  stage_half(B, brow0 + 128, 0, Bslot + 1 * HALF_B, tid);
  stage_half(A, arow0, 1, Aslot + 2 * HALF_B, tid);
  asm volatile("s_waitcnt vmcnt(2)" ::: "memory");
  asm volatile("s_barrier" ::: "memory");

  int sA = 0;  // (2t)%5
  int sB = 0;  // (2t)%4
  for (int t = 0; t < NT; ++t) {
    const char* aB = Aslot + (((sA + wr) >= 5) ? (sA + wr - 5) : (sA + wr)) * HALF_B;
    const char* bB = Bslot + ((sB + (wc >> 1)) & 3) * HALF_B;

    // ---- PH1 reads + stage A1,B0,B1 of t+1
    if (!par) {
#pragma unroll
      for (int mb = 0; mb < 2; ++mb)
#pragma unroll
        for (int ks = 0; ks < 4; ++ks)
          afA[mb][ks] = ld_frag(aB, mb * 32 + lc, ks * 2 + lh);
#pragma unroll
      for (int ks = 0; ks < 4; ++ks)
        bfA[ks] = ld_frag(bB, bcol0 + lc, ks * 2 + lh);
    } else {
#pragma unroll
      for (int mb = 0; mb < 2; ++mb)
#pragma unroll
        for (int ks = 0; ks < 4; ++ks)
          afB[mb][ks] = ld_frag(aB, (2 + mb) * 32 + lc, ks * 2 + lh);
#pragma unroll
      for (int ks = 0; ks < 4; ++ks)
        bfB[ks] = ld_frag(bB, bcol0 + 32 + lc, ks * 2 + lh);
    }
    if (t + 1 < NT) {
      int s1 = sA + 3; if (s1 >= 5) s1 -= 5;
      stage_half(A, arow0 + 128, t + 1, Aslot + s1 * HALF_B, tid);
      stage_half(B, brow0, t + 1, Bslot + ((sB + 2) & 3) * HALF_B, tid);
      stage_half(B, brow0 + 128, t + 1, Bslot + ((sB + 3) & 3) * HALF_B, tid);
    }
    __builtin_amdgcn_s_setprio(1);
    if (!par) {
#pragma unroll
      for (int mb = 0; mb < 2; ++mb)
#pragma unroll
        for (int ks = 0; ks < 4; ++ks)
          acc[mb][0] = __builtin_amdgcn_mfma_f32_32x32x16_bf16(afA[mb][ks], bfA[ks], acc[mb][0], 0, 0, 0);
    } else {
#pragma unroll
      for (int mb = 0; mb < 2; ++mb)
#pragma unroll
        for (int ks = 0; ks < 4; ++ks)
          acc[2 + mb][1] = __builtin_amdgcn_mfma_f32_32x32x16_bf16(afB[mb][ks], bfB[ks], acc[2 + mb][1], 0, 0, 0);
    }
    __builtin_amdgcn_s_setprio(0);

    // ---- PH2 reads + stage A0(t+2)
    if (!par) {
#pragma unroll
      for (int ks = 0; ks < 4; ++ks)
        bfB[ks] = ld_frag(bB, bcol0 + 32 + lc, ks * 2 + lh);
    } else {
#pragma unroll
      for (int ks = 0; ks < 4; ++ks)
        bfA[ks] = ld_frag(bB, bcol0 + lc, ks * 2 + lh);
    }
    if (t + 2 < NT) {
      int s2 = sA + 4; if (s2 >= 5) s2 -= 5;
      stage_half(A, arow0, t + 2, Aslot + s2 * HALF_B, tid);
    }
    __builtin_amdgcn_s_setprio(1);
    if (!par) {
#pragma unroll
      for (int mb = 0; mb < 2; ++mb)
#pragma unroll
        for (int ks = 0; ks < 4; ++ks)
          acc[mb][1] = __builtin_amdgcn_mfma_f32_32x32x16_bf16(afA[mb][ks], bfB[ks], acc[mb][1], 0, 0, 0);
    } else {
#pragma unroll
      for (int mb = 0; mb < 2; ++mb)
#pragma unroll
        for (int ks = 0; ks < 4; ++ks)
          acc[2 + mb][0] = __builtin_amdgcn_mfma_f32_32x32x16_bf16(afB[mb][ks], bfA[ks], acc[2 + mb][0], 0, 0, 0);
    }
    __builtin_amdgcn_s_setprio(0);

    // ---- PH3 reads
    if (!par) {
#pragma unroll
      for (int mb = 0; mb < 2; ++mb)
#pragma unroll
        for (int ks = 0; ks < 4; ++ks)
          afB[mb][ks] = ld_frag(aB, (2 + mb) * 32 + lc, ks * 2 + lh);
    } else {
#pragma unroll
      for (int mb = 0; mb < 2; ++mb)
#pragma unroll
        for (int ks = 0; ks < 4; ++ks)
          afA[mb][ks] = ld_frag(aB, mb * 32 + lc, ks * 2 + lh);
    }
    __builtin_amdgcn_s_setprio(1);
    if (!par) {
#pragma unroll
      for (int mb = 0; mb < 2; ++mb)
#pragma unroll
        for (int ks = 0; ks < 4; ++ks)
          acc[2 + mb][1] = __builtin_amdgcn_mfma_f32_32x32x16_bf16(afB[mb][ks], bfB[ks], acc[2 + mb][1], 0, 0, 0);
    } else {
#pragma unroll
      for (int mb = 0; mb < 2; ++mb)
#pragma unroll
        for (int ks = 0; ks < 4; ++ks)
          acc[mb][0] = __builtin_amdgcn_mfma_f32_32x32x16_bf16(afA[mb][ks], bfA[ks], acc[mb][0], 0, 0, 0);
    }
    __builtin_amdgcn_s_setprio(0);

    // ---- PH4 (no LDS reads)
    __builtin_amdgcn_s_setprio(1);
    if (!par) {
#pragma unroll
      for (int mb = 0; mb < 2; ++mb)
#pragma unroll
        for (int ks = 0; ks < 4; ++ks)
          acc[2 + mb][0] = __builtin_amdgcn_mfma_f32_32x32x16_bf16(afB[mb][ks], bfA[ks], acc[2 + mb][0], 0, 0, 0);
    } else {
#pragma unroll
      for (int mb = 0; mb < 2; ++mb)
#pragma unroll
        for (int ks = 0; ks < 4; ++ks)
          acc[mb][1] = __builtin_amdgcn_mfma_f32_32x32x16_bf16(afA[mb][ks], bfB[ks], acc[mb][1], 0, 0, 0);
    }
    __builtin_amdgcn_s_setprio(0);
    // steady state: drain the 6 t+1 half-tile loads, keep A0(t+2) in flight.
    if (t + 2 < NT) {
      asm volatile("s_waitcnt vmcnt(2)" ::: "memory");
    } else {
      asm volatile("s_waitcnt vmcnt(0)" ::: "memory");
    }
    asm volatile("s_barrier" ::: "memory");

    sA += 2; if (sA >= 5) sA -= 5;
    sB ^= 2;
  }

  // ---- epilogue: diag->1, * adj_v, bf16 store (32x32 C/D layout)
#pragma unroll
  for (int mb = 0; mb < 4; ++mb) {
#pragma unroll
    for (int nb = 0; nb < 2; ++nb) {
      int gcol = bj * 256 + wc * 64 + nb * 32 + lc;
#pragma unroll
      for (int r = 0; r < 16; ++r) {
        int grow = bi * 256 + wr * 128 + mb * 32 + (r & 3) + 8 * (r >> 2) + 4 * lh;
        float v = acc[mb][nb][r];
        if (grow == gcol) v = 1.0f;
        adjA[(size_t)grow * NV + gcol] = f2bf(v * adj_v[(size_t)grow * NV + gcol]);
      }
    }
  }
}

// partial = adjA[bi*128..][krange] @ XT^T[krange]  (K-split 8 -> 256 blocks)
__global__ __launch_bounds__(256) void k_gemm2p(const uint16_t* __restrict__ A,
                                                const uint16_t* __restrict__ B,
                                                float* __restrict__ part) {
  __shared__ __align__(16) uint16_t As[128 * 32];
  __shared__ __align__(16) uint16_t Bs[128 * 32];
  const int tid = threadIdx.x;
  const int wid = tid >> 6, lane = tid & 63;
  const int wr = wid >> 1, wc = wid & 1;
  const int ks = blockIdx.x & 7;
  const int bi = blockIdx.x >> 3;
  const int lr = lane & 15, lk = lane >> 4;

  f32x4 acc[4][4] = {};

  for (int kt = ks * 16; kt < ks * 16 + 16; ++kt) {
#pragma unroll
    for (int i = 0; i < 2; ++i) {
      int o = (wid * 2 + i) * 1024 + lane * 16;
      int row = o >> 6, kb = o & 63;
      const char* ga = (const char*)A + ((size_t)(bi * 128 + row) * NV + kt * 32) * 2 + kb;
      const char* gb = (const char*)B + ((size_t)row * NV + kt * 32) * 2 + kb;
      __builtin_amdgcn_global_load_lds(
          (const __attribute__((address_space(1))) uint32_t*)ga,
          (__attribute__((address_space(3))) uint32_t*)((char*)As + (wid * 2 + i) * 1024),
          16, 0, 0);
      __builtin_amdgcn_global_load_lds(
          (const __attribute__((address_space(1))) uint32_t*)gb,
          (__attribute__((address_space(3))) uint32_t*)((char*)Bs + (wid * 2 + i) * 1024),
          16, 0, 0);
    }
    __syncthreads();
    bf16x8 af[4], bfr[4];
#pragma unroll
    for (int m = 0; m < 4; ++m)
      af[m] = *(const bf16x8*)&As[(wr * 64 + m * 16 + lr) * 32 + lk * 8];
#pragma unroll
    for (int n = 0; n < 4; ++n)
      bfr[n] = *(const bf16x8*)&Bs[(wc * 64 + n * 16 + lr) * 32 + lk * 8];
#pragma unroll
    for (int m = 0; m < 4; ++m)
#pragma unroll
      for (int n = 0; n < 4; ++n)
        acc[m][n] = __builtin_amdgcn_mfma_f32_16x16x32_bf16(af[m], bfr[n], acc[m][n], 0, 0, 0);
    __syncthreads();
  }

  float* my = part + (size_t)ks * NV * OUTV;
#pragma unroll
  for (int m = 0; m < 4; ++m) {
    int grow0 = bi * 128 + wr * 64 + m * 16 + lk * 4;
#pragma unroll
    for (int n = 0; n < 4; ++n) {
      int gcol = wc * 64 + n * 16 + lr;
#pragma unroll
      for (int r = 0; r < 4; ++r)
        my[(size_t)(grow0 + r) * OUTV + gcol] = acc[m][n][r];
    }
  }
}

// out = sum_ks part[ks] + bias
__global__ void k_gemm2r(const float4* __restrict__ part, const float* __restrict__ bias,
                         float4* __restrict__ out) {
  int i = blockIdx.x * 256 + threadIdx.x;  // 131072 float4 positions
  float4 s = part[i];
#pragma unroll
  for (int ks = 1; ks < 8; ++ks) {
    float4 q = part[(size_t)ks * (NV * OUTV / 4) + i];
    s.x += q.x; s.y += q.y; s.z += q.z; s.w += q.w;
  }
  float4 b = ((const float4*)bias)[i & 31];
  s.x += b.x; s.y += b.y; s.z += b.z; s.w += b.w;
  out[i] = s;
}

extern "C" void kernel_launch(void* const* d_in, const int* in_sizes, int n_in,
                              void* d_out, int out_size, void* d_ws, size_t ws_size,
                              hipStream_t stream) {
  const float* Hv = (const float*)d_in[0];
  const float* He = (const float*)d_in[1];
  // d_in[2] = adj_e — UNUSED by the reference
  const float* adj_v = (const float*)d_in[3];
  const float* T = (const float*)d_in[4];
  const float* W = (const float*)d_in[5];
  const float* bias = (const float*)d_in[6];
  const float* p = (const float*)d_in[7];
  float* out = (float*)d_out;

  char* ws = (char*)d_ws;
  float* dvec = (float*)ws;                                   // 32 KB
  uint16_t* XT = (uint16_t*)(ws + 32768);                     // 1 MB
  uint16_t* Abf = (uint16_t*)(ws + 32768 + (1u << 20));       // 64 MB
  uint16_t* Bbf = Abf + (size_t)NV * NE;                      // 64 MB
  uint16_t* adjA = Bbf + (size_t)NV * NE;                     // 32 MB
  float* part = (float*)Abf;  // reuse: Abf is dead after k_gemm1 (16 MB needed)

  static int lds_attr_set = 0;
  if (!lds_attr_set) {
    hipFuncSetAttribute((const void*)k_gemm1,
                        hipFuncAttributeMaxDynamicSharedMemorySize, LDS_BYTES);
    lds_attr_set = 1;
  }

  k_diag<<<NE / 4, 256, 0, stream>>>(He, p, dvec);
  k_prep<<<2048, 256, 0, stream>>>((const float4*)T, (const float4*)dvec,
                                   (ushort4*)Abf, (ushort4*)Bbf);
  k_xw<<<NV, INV, 0, stream>>>(Hv, W, XT);
  k_gemm1<<<256, 512, LDS_BYTES, stream>>>(Abf, Bbf, adj_v, adjA);
  k_gemm2p<<<256, 256, 0, stream>>>(adjA, XT, part);
  k_gemm2r<<<NV * OUTV / 4 / 256, 256, 0, stream>>>((const float4*)part, bias, (float4*)out);
  hipMemcpyAsync(out + (size_t)NV * OUTV, He, (size_t)NE * INE * sizeof(float),
                 hipMemcpyDeviceToDevice, stream);
}

// Round 7
// 288.993 us; speedup vs baseline: 1.2435x; 1.2435x over previous
//
#include <hip/hip_runtime.h>
#include <cstdint>
#include <cstddef>

#define NV 4096
#define NE 8192
#define INV 128
#define OUTV 128
#define INE 64

#define BK 64
#define NT (NE / BK)        // 128 K-tiles
#define HALF_B 16384        // 128 rows x 64 bf16 x 2B
#define LDS_BYTES (9 * HALF_B)  // 5 A-slots + 4 B-slots = 144 KiB

typedef __bf16 bf16x8 __attribute__((ext_vector_type(8)));
typedef float f32x4 __attribute__((ext_vector_type(4)));

__device__ __forceinline__ uint16_t f2bf(float x) {
  uint32_t u = __builtin_bit_cast(uint32_t, x);
  u += 0x7fff + ((u >> 16) & 1);
  return (uint16_t)(u >> 16);
}

// d[e] = dot(H_e[e, :64], p[:64]); one wave per row
__global__ void k_diag(const float* __restrict__ He, const float* __restrict__ p,
                       float* __restrict__ d) {
  int lane = threadIdx.x & 63;
  int wid = threadIdx.x >> 6;
  int row = blockIdx.x * 4 + wid;
  float v = He[(size_t)row * INE + lane] * p[lane];
#pragma unroll
  for (int off = 32; off; off >>= 1) v += __shfl_xor(v, off);
  if (lane == 0) d[row] = v;
}

// Abf = bf16(T * d[col]), Bbf = bf16(T)   (both [NV][NE] row-major)
__global__ void k_prep(const float4* __restrict__ T4, const float4* __restrict__ d4,
                       ushort4* __restrict__ A4, ushort4* __restrict__ B4) {
  const size_t total = (size_t)NV * NE / 4;
  size_t stride = (size_t)gridDim.x * blockDim.x;
  for (size_t i = (size_t)blockIdx.x * blockDim.x + threadIdx.x; i < total; i += stride) {
    float4 t = T4[i];
    float4 dv = d4[i & (NE / 4 - 1)];
    ushort4 a, b;
    b.x = f2bf(t.x); b.y = f2bf(t.y); b.z = f2bf(t.z); b.w = f2bf(t.w);
    a.x = f2bf(t.x * dv.x); a.y = f2bf(t.y * dv.y);
    a.z = f2bf(t.z * dv.z); a.w = f2bf(t.w * dv.w);
    A4[i] = a;
    B4[i] = b;
  }
}

// XT[n][m] = bf16( sum_k H_v[m][k] * W[k][n] )   (X^T, [OUTV][NV])
__global__ void k_xw(const float* __restrict__ Hv, const float* __restrict__ W,
                     uint16_t* __restrict__ XT) {
  __shared__ float row[INV];
  int m = blockIdx.x;
  int n = threadIdx.x;  // 128 threads
  row[n] = Hv[(size_t)m * INV + n];
  __syncthreads();
  float acc = 0.f;
#pragma unroll 8
  for (int k = 0; k < INV; ++k) acc += row[k] * W[k * OUTV + n];
  XT[(size_t)n * NV + m] = f2bf(acc);
}

// ---- 256x256x64 bf16 GEMM, 1 barrier/K-tile, intra-tile SW pipeline ----
// C = A @ B^T over K=NE; epilogue: diag->1, * adj_v, store bf16

// stage one 128-row x 64-col half-tile; linear LDS dest, inverse-swizzled
// global source (slot ^= row&7 at 16B granularity within the 128B row).
__device__ __forceinline__ void stage_half(const uint16_t* __restrict__ G, int grow0,
                                           int ktile, char* lds_base, int tid) {
#pragma unroll
  for (int i = 0; i < 2; ++i) {
    int idx = i * 512 + tid;
    int row = idx >> 3;
    int slot = (idx & 7) ^ (row & 7);
    const char* src = (const char*)G +
        ((size_t)(grow0 + row) * NE + (size_t)ktile * BK) * 2 + slot * 16;
    __builtin_amdgcn_global_load_lds(
        (const __attribute__((address_space(1))) uint32_t*)src,
        (__attribute__((address_space(3))) uint32_t*)(lds_base + idx * 16), 16, 0, 0);
  }
}

__device__ __forceinline__ bf16x8 ld_frag(const char* half_base, int row, int g) {
  return *(const bf16x8*)(half_base + row * 128 + ((g ^ (row & 7)) << 4));
}

__global__ __launch_bounds__(512, 2) void k_gemm1(const uint16_t* __restrict__ A,
                                                  const uint16_t* __restrict__ B,
                                                  const float* __restrict__ adj_v,
                                                  uint16_t* __restrict__ adjA) {
  extern __shared__ char smem[];
  char* Aslot = smem;                 // 5 x HALF_B
  char* Bslot = smem + 5 * HALF_B;    // 4 x HALF_B

  const int tid = threadIdx.x;
  const int lane = tid & 63, wid = tid >> 6;
  const int wr = wid >> 2, wc = wid & 3;
  const int lr = lane & 15, lk = lane >> 4;
  const int bcol0 = (wc & 1) * 64;

  // XCD-aware swizzle: 256 blocks -> 8 chunks of 32; each chunk a 4(bi) x 8(bj) rect
  int bid = blockIdx.x;
  int xcd = bid & 7, cid = bid >> 3;
  int bi = (xcd >> 1) * 4 + (cid >> 3);
  int bj = (xcd & 1) * 8 + (cid & 7);

  const int arow0 = bi * 256, brow0 = bj * 256;

  f32x4 acc[8][4] = {};
  bf16x8 af[4][2], af2[4][2], bfr[2][2], bfr2[2][2];

  // ---- prologue: tile0 all halves + A0(tile1)
  stage_half(A, arow0, 0, Aslot + 0 * HALF_B, tid);
  stage_half(A, arow0 + 128, 0, Aslot + 1 * HALF_B, tid);
  stage_half(B, brow0, 0, Bslot + 0 * HALF_B, tid);
  stage_half(B, brow0 + 128, 0, Bslot + 1 * HALF_B, tid);
  stage_half(A, arow0, 1, Aslot + 2 * HALF_B, tid);
  asm volatile("s_waitcnt vmcnt(2)" ::: "memory");
  asm volatile("s_barrier" ::: "memory");

  int sA = 0;  // (2t)%5
  int sB = 0;  // (2t)%4
  for (int t = 0; t < NT; ++t) {
    const char* aB = Aslot + (((sA + wr) >= 5) ? (sA + wr - 5) : (sA + wr)) * HALF_B;
    const char* bB = Bslot + ((sB + (wc >> 1)) & 3) * HALF_B;

    // ---- R1: Q00 operands (af, bfr); stage A1,B0,B1 of t+1
#pragma unroll
    for (int m = 0; m < 4; ++m)
#pragma unroll
      for (int kk = 0; kk < 2; ++kk)
        af[m][kk] = ld_frag(aB, m * 16 + lr, kk * 4 + lk);
#pragma unroll
    for (int n = 0; n < 2; ++n)
#pragma unroll
      for (int kk = 0; kk < 2; ++kk)
        bfr[n][kk] = ld_frag(bB, bcol0 + n * 16 + lr, kk * 4 + lk);
    if (t + 1 < NT) {
      int s1 = sA + 3; if (s1 >= 5) s1 -= 5;
      stage_half(A, arow0 + 128, t + 1, Aslot + s1 * HALF_B, tid);
      stage_half(B, brow0, t + 1, Bslot + ((sB + 2) & 3) * HALF_B, tid);
      stage_half(B, brow0 + 128, t + 1, Bslot + ((sB + 3) & 3) * HALF_B, tid);
    }

    // ---- R2: Q01's B operand issued BEFORE Q00's MFMA burst (1-phase lookahead)
#pragma unroll
    for (int n = 0; n < 2; ++n)
#pragma unroll
      for (int kk = 0; kk < 2; ++kk)
        bfr2[n][kk] = ld_frag(bB, bcol0 + (2 + n) * 16 + lr, kk * 4 + lk);

    // ---- MFMA Q00
#pragma unroll
    for (int m = 0; m < 4; ++m)
#pragma unroll
      for (int n = 0; n < 2; ++n)
#pragma unroll
        for (int kk = 0; kk < 2; ++kk)
          acc[m][n] = __builtin_amdgcn_mfma_f32_16x16x32_bf16(af[m][kk], bfr[n][kk], acc[m][n], 0, 0, 0);

    // ---- stage A0(t+2); R3: Q11's A operand issued BEFORE Q01's MFMA burst
    if (t + 2 < NT) {
      int s2 = sA + 4; if (s2 >= 5) s2 -= 5;
      stage_half(A, arow0, t + 2, Aslot + s2 * HALF_B, tid);
    }
#pragma unroll
    for (int m = 0; m < 4; ++m)
#pragma unroll
      for (int kk = 0; kk < 2; ++kk)
        af2[m][kk] = ld_frag(aB, (4 + m) * 16 + lr, kk * 4 + lk);

    // ---- MFMA Q01
#pragma unroll
    for (int m = 0; m < 4; ++m)
#pragma unroll
      for (int n = 0; n < 2; ++n)
#pragma unroll
        for (int kk = 0; kk < 2; ++kk)
          acc[m][2 + n] = __builtin_amdgcn_mfma_f32_16x16x32_bf16(af[m][kk], bfr2[n][kk], acc[m][2 + n], 0, 0, 0);

    // ---- MFMA Q11
#pragma unroll
    for (int m = 0; m < 4; ++m)
#pragma unroll
      for (int n = 0; n < 2; ++n)
#pragma unroll
        for (int kk = 0; kk < 2; ++kk)
          acc[4 + m][2 + n] = __builtin_amdgcn_mfma_f32_16x16x32_bf16(af2[m][kk], bfr2[n][kk], acc[4 + m][2 + n], 0, 0, 0);

    // ---- MFMA Q10
#pragma unroll
    for (int m = 0; m < 4; ++m)
#pragma unroll
      for (int n = 0; n < 2; ++n)
#pragma unroll
        for (int kk = 0; kk < 2; ++kk)
          acc[4 + m][n] = __builtin_amdgcn_mfma_f32_16x16x32_bf16(af2[m][kk], bfr[n][kk], acc[4 + m][n], 0, 0, 0);

    // steady state: drain the 6 t+1 half-tile loads, keep A0(t+2) in flight.
    // tail (no A0(t+2) staged): drain everything.
    if (t + 2 < NT) {
      asm volatile("s_waitcnt vmcnt(2)" ::: "memory");
    } else {
      asm volatile("s_waitcnt vmcnt(0)" ::: "memory");
    }
    asm volatile("s_barrier" ::: "memory");

    sA += 2; if (sA >= 5) sA -= 5;
    sB ^= 2;
  }

  // ---- epilogue: diag->1, * adj_v, bf16 store
#pragma unroll
  for (int m = 0; m < 8; ++m) {
    int grow0 = bi * 256 + wr * 128 + m * 16 + lk * 4;
#pragma unroll
    for (int n = 0; n < 4; ++n) {
      int gcol = bj * 256 + wc * 64 + n * 16 + lr;
#pragma unroll
      for (int r = 0; r < 4; ++r) {
        int grow = grow0 + r;
        float v = acc[m][n][r];
        if (grow == gcol) v = 1.0f;
        adjA[(size_t)grow * NV + gcol] = f2bf(v * adj_v[(size_t)grow * NV + gcol]);
      }
    }
  }
}

// partial = adjA[bi*128..][krange] @ XT^T[krange]  (K-split 8 -> 256 blocks)
__global__ __launch_bounds__(256) void k_gemm2p(const uint16_t* __restrict__ A,
                                                const uint16_t* __restrict__ B,
                                                float* __restrict__ part) {
  __shared__ __align__(16) uint16_t As[128 * 32];
  __shared__ __align__(16) uint16_t Bs[128 * 32];
  const int tid = threadIdx.x;
  const int wid = tid >> 6, lane = tid & 63;
  const int wr = wid >> 1, wc = wid & 1;
  const int ks = blockIdx.x & 7;
  const int bi = blockIdx.x >> 3;
  const int lr = lane & 15, lk = lane >> 4;

  f32x4 acc[4][4] = {};

  for (int kt = ks * 16; kt < ks * 16 + 16; ++kt) {
#pragma unroll
    for (int i = 0; i < 2; ++i) {
      int o = (wid * 2 + i) * 1024 + lane * 16;
      int row = o >> 6, kb = o & 63;
      const char* ga = (const char*)A + ((size_t)(bi * 128 + row) * NV + kt * 32) * 2 + kb;
      const char* gb = (const char*)B + ((size_t)row * NV + kt * 32) * 2 + kb;
      __builtin_amdgcn_global_load_lds(
          (const __attribute__((address_space(1))) uint32_t*)ga,
          (__attribute__((address_space(3))) uint32_t*)((char*)As + (wid * 2 + i) * 1024),
          16, 0, 0);
      __builtin_amdgcn_global_load_lds(
          (const __attribute__((address_space(1))) uint32_t*)gb,
          (__attribute__((address_space(3))) uint32_t*)((char*)Bs + (wid * 2 + i) * 1024),
          16, 0, 0);
    }
    __syncthreads();
    bf16x8 af[4], bfr[4];
#pragma unroll
    for (int m = 0; m < 4; ++m)
      af[m] = *(const bf16x8*)&As[(wr * 64 + m * 16 + lr) * 32 + lk * 8];
#pragma unroll
    for (int n = 0; n < 4; ++n)
      bfr[n] = *(const bf16x8*)&Bs[(wc * 64 + n * 16 + lr) * 32 + lk * 8];
#pragma unroll
    for (int m = 0; m < 4; ++m)
#pragma unroll
      for (int n = 0; n < 4; ++n)
        acc[m][n] = __builtin_amdgcn_mfma_f32_16x16x32_bf16(af[m], bfr[n], acc[m][n], 0, 0, 0);
    __syncthreads();
  }

  float* my = part + (size_t)ks * NV * OUTV;
#pragma unroll
  for (int m = 0; m < 4; ++m) {
    int grow0 = bi * 128 + wr * 64 + m * 16 + lk * 4;
#pragma unroll
    for (int n = 0; n < 4; ++n) {
      int gcol = wc * 64 + n * 16 + lr;
#pragma unroll
      for (int r = 0; r < 4; ++r)
        my[(size_t)(grow0 + r) * OUTV + gcol] = acc[m][n][r];
    }
  }
}

// out = sum_ks part[ks] + bias
__global__ void k_gemm2r(const float4* __restrict__ part, const float* __restrict__ bias,
                         float4* __restrict__ out) {
  int i = blockIdx.x * 256 + threadIdx.x;  // 131072 float4 positions
  float4 s = part[i];
#pragma unroll
  for (int ks = 1; ks < 8; ++ks) {
    float4 q = part[(size_t)ks * (NV * OUTV / 4) + i];
    s.x += q.x; s.y += q.y; s.z += q.z; s.w += q.w;
  }
  float4 b = ((const float4*)bias)[i & 31];
  s.x += b.x; s.y += b.y; s.z += b.z; s.w += b.w;
  out[i] = s;
}

extern "C" void kernel_launch(void* const* d_in, const int* in_sizes, int n_in,
                              void* d_out, int out_size, void* d_ws, size_t ws_size,
                              hipStream_t stream) {
  const float* Hv = (const float*)d_in[0];
  const float* He = (const float*)d_in[1];
  // d_in[2] = adj_e — UNUSED by the reference
  const float* adj_v = (const float*)d_in[3];
  const float* T = (const float*)d_in[4];
  const float* W = (const float*)d_in[5];
  const float* bias = (const float*)d_in[6];
  const float* p = (const float*)d_in[7];
  float* out = (float*)d_out;

  char* ws = (char*)d_ws;
  float* dvec = (float*)ws;                                   // 32 KB
  uint16_t* XT = (uint16_t*)(ws + 32768);                     // 1 MB
  uint16_t* Abf = (uint16_t*)(ws + 32768 + (1u << 20));       // 64 MB
  uint16_t* Bbf = Abf + (size_t)NV * NE;                      // 64 MB
  uint16_t* adjA = Bbf + (size_t)NV * NE;                     // 32 MB
  float* part = (float*)Abf;  // reuse: Abf is dead after k_gemm1 (16 MB needed)

  static int lds_attr_set = 0;
  if (!lds_attr_set) {
    hipFuncSetAttribute((const void*)k_gemm1,
                        hipFuncAttributeMaxDynamicSharedMemorySize, LDS_BYTES);
    lds_attr_set = 1;
  }

  k_diag<<<NE / 4, 256, 0, stream>>>(He, p, dvec);
  k_prep<<<2048, 256, 0, stream>>>((const float4*)T, (const float4*)dvec,
                                   (ushort4*)Abf, (ushort4*)Bbf);
  k_xw<<<NV, INV, 0, stream>>>(Hv, W, XT);
  k_gemm1<<<256, 512, LDS_BYTES, stream>>>(Abf, Bbf, adj_v, adjA);
  k_gemm2p<<<256, 256, 0, stream>>>(adjA, XT, part);
  k_gemm2r<<<NV * OUTV / 4 / 256, 256, 0, stream>>>((const float4*)part, bias, (float4*)out);
  hipMemcpyAsync(out + (size_t)NV * OUTV, He, (size_t)NE * INE * sizeof(float),
                 hipMemcpyDeviceToDevice, stream);
}